// Round 3
// baseline (468.903 us; speedup 1.0000x reference)
//
#include <hip/hip_runtime.h>
#include <hip/hip_bf16.h>
#include <cstdint>
#include <cstddef>

// Problem constants (T,B,D,H,L = 1024,64,512,512,2)
#define T_DIM 1024
#define B_DIM 64
#define D_DIM 512
#define H_DIM 512
#define TBROWS (T_DIM * B_DIM)           // 65536 GEMM rows
#define BH (B_DIM * H_DIM)               // 32768
#define TBH ((size_t)T_DIM * (size_t)BH) // 33554432 elements

typedef __bf16 bf16x8 __attribute__((ext_vector_type(8)));
typedef float floatx4 __attribute__((ext_vector_type(4)));

// ---------------------------------------------------------------------------
// async global->LDS, 16B per lane. LDS dest is wave-uniform base + lane*16.
// ---------------------------------------------------------------------------
__device__ __forceinline__ void async_load16(const void* g, void* l) {
  __builtin_amdgcn_global_load_lds(
      (const __attribute__((address_space(1))) unsigned int*)g,
      (__attribute__((address_space(3))) unsigned int*)l,
      16, 0, 0);
}

// counted vmcnt wait (compile-time literal via switch)
__device__ __forceinline__ void wait_vm(int n) {
  switch (n) {
    case 4:  asm volatile("s_waitcnt vmcnt(4)"  ::: "memory"); break;
    case 6:  asm volatile("s_waitcnt vmcnt(6)"  ::: "memory"); break;
    case 8:  asm volatile("s_waitcnt vmcnt(8)"  ::: "memory"); break;
    case 12: asm volatile("s_waitcnt vmcnt(12)" ::: "memory"); break;
    case 16: asm volatile("s_waitcnt vmcnt(16)" ::: "memory"); break;
    case 24: asm volatile("s_waitcnt vmcnt(24)" ::: "memory"); break;
    case 32: asm volatile("s_waitcnt vmcnt(32)" ::: "memory"); break;
    case 40: asm volatile("s_waitcnt vmcnt(40)" ::: "memory"); break;
    case 48: asm volatile("s_waitcnt vmcnt(48)" ::: "memory"); break;
    default: asm volatile("s_waitcnt vmcnt(0)"  ::: "memory"); break;
  }
}

// ---------------------------------------------------------------------------
// Merged prep:
//   blocks [0,128):    Wc[h,d] = sum_e w0[h,e]*fc_w[e,d] (bf16), 8 h-rows/blk
//   blocks [128,256):  w1 -> bf16
//   blocks [256,258):  bcomb[h] = b0[h] + sum_e w0[h,e]*fc_b[e]
// ---------------------------------------------------------------------------
__global__ __launch_bounds__(256) void prep_kernel(
    const float* __restrict__ w0, const float* __restrict__ fc_w,
    const float* __restrict__ fc_b, const float* __restrict__ b0,
    const float* __restrict__ w1, __bf16* __restrict__ Wc,
    __bf16* __restrict__ w1bf, float* __restrict__ bcomb) {
  const int blk = blockIdx.x;
  const int tid = threadIdx.x;
  if (blk < 128) {
    const int h0 = (blk >> 1) * 8;
    const int d = ((blk & 1) << 8) + tid;
    float a[8];
#pragma unroll
    for (int j = 0; j < 8; j++) a[j] = 0.f;
#pragma unroll 4
    for (int e = 0; e < D_DIM; ++e) {
      const float fv = fc_w[(size_t)e * D_DIM + d];
#pragma unroll
      for (int j = 0; j < 8; j++)
        a[j] = fmaf(w0[(size_t)(h0 + j) * D_DIM + e], fv, a[j]);  // w0: s_load
    }
#pragma unroll
    for (int j = 0; j < 8; j++)
      Wc[(size_t)(h0 + j) * D_DIM + d] = (__bf16)a[j];
  } else if (blk < 256) {
    const long i = ((long)(blk - 128) * 256 + tid) * 8;
    const float4 a = *(const float4*)(w1 + i);
    const float4 b = *(const float4*)(w1 + i + 4);
    bf16x8 v;
    v[0] = (__bf16)a.x; v[1] = (__bf16)a.y; v[2] = (__bf16)a.z; v[3] = (__bf16)a.w;
    v[4] = (__bf16)b.x; v[5] = (__bf16)b.y; v[6] = (__bf16)b.z; v[7] = (__bf16)b.w;
    *(bf16x8*)(w1bf + i) = v;
  } else {
    const int h = (blk - 256) * 256 + tid;
    float acc = b0[h];
    const float4* w4 = (const float4*)(w0 + (size_t)h * D_DIM);
#pragma unroll 4
    for (int e = 0; e < D_DIM / 4; ++e) {
      const float4 wv = w4[e];
      acc = fmaf(wv.x, fc_b[e * 4 + 0], acc);
      acc = fmaf(wv.y, fc_b[e * 4 + 1], acc);
      acc = fmaf(wv.z, fc_b[e * 4 + 2], acc);
      acc = fmaf(wv.w, fc_b[e * 4 + 3], acc);
    }
    bcomb[h] = acc;
  }
}

// ---------------------------------------------------------------------------
// GEMMs: 128x128 tile, BK=32, 4 waves 2x2, 16x16x32 MFMA.
// Counted-vmcnt depth-2 pipeline (T3+T4 port):
//   3-deep LDS ring; per iteration:
//     wait vmcnt(2*loads_per_tile)   <- own tile-t loads done; t+1,t+2 in flight
//     s_barrier                      <- all waves certified: tile t ready
//     ds_read frags + MFMA
//     sched_barrier(0)               <- pin reads+MFMA above barrier2
//     s_barrier                      <- buffer t%3 now reusable by anyone
//     stage tile t+3 into buffer t%3
//   NO vmcnt(0) in the main loop: waited-on loads were issued ~2 full
//   iterations earlier.
// bf16 tiles use both-sides XOR swizzle: source slot p ^ ((row>>1)&3), same
// XOR on the read side; f32 A tile uses slot ^ (row&7). Both 2-way (free).
// ---------------------------------------------------------------------------
#define BM 128
#define BN 128
#define BK 32

__device__ __forceinline__ int xcd_swizzle(int bid, int nwg) {
  // nwg % 8 == 0 for all launches here -> simple bijective form (m157/m204)
  return (bid & 7) * (nwg >> 3) + (bid >> 3);
}

// Variant A: A is f32 (raw x input), f32->bf16 fused into the fragment path.
__global__ __launch_bounds__(256) void gemm_a32_bt_bias(
    const float* __restrict__ A,    // [M,K] f32
    const __bf16* __restrict__ Bm,  // [N,K] bf16
    const float* __restrict__ bias, // [N]
    __bf16* __restrict__ C,         // [M,N] bf16
    int M, int N, int K) {
  __shared__ float Asf[3][BM * BK];   // 3 x 16 KB
  __shared__ __bf16 Bs[3][BN * BK];   // 3 x 8 KB   (72 KB total)

  const int tid = threadIdx.x;
  const int lane = tid & 63;
  const int wave = tid >> 6;
  const int wg = xcd_swizzle((int)blockIdx.x, (int)gridDim.x);
  const int nb = N / BN;
  const int bm = wg / nb;
  const int bn = wg % nb;
  const int m0 = bm * BM, n0 = bn * BN;

  floatx4 zero = {0.f, 0.f, 0.f, 0.f};
  floatx4 acc[4][4];
#pragma unroll
  for (int i = 0; i < 4; i++)
#pragma unroll
    for (int j = 0; j < 4; j++) acc[i][j] = zero;

  // B staging map: 4 lanes/row, physical slot p=e&3, source slot p^((r>>1)&3)
  const int e0 = (wave * 2 + 0) * 64 + lane;
  const int e1 = (wave * 2 + 1) * 64 + lane;
  const int r0 = e0 >> 2, g0 = (e0 & 3) ^ ((r0 >> 1) & 3);
  const int r1 = e1 >> 2, g1 = (e1 & 3) ^ ((r1 >> 1) & 3);

  const int tm = (wave >> 1) * 64;
  const int tn = (wave & 1) * 64;
  const int lrow = lane & 15;
  const int lk = (lane >> 4) * 8;
  const int sB = lk >> 3;       // bf16 16B-slot index 0..3
  const int s0 = lk >> 2;       // f32 16B-slot index {0,2,4,6}

  // A staging map: 8 lanes/row (128B), physical slot p=e&7, source p^(r&7)
  const int ea = wave * 4;

  const int KT = K / BK;

  // ---- stage K-tile kt into ring buffer b (6 loads per wave) ----
  auto stage = [&](int b, int kt) {
    const int k0 = kt * BK;
#pragma unroll
    for (int i = 0; i < 4; i++) {
      const int e = (ea + i) * 64 + lane;
      const int r = e >> 3;
      const int g = (e & 7) ^ (r & 7);
      async_load16(&A[(size_t)(m0 + r) * K + k0 + g * 4],
                   &Asf[b][(ea + i) * 256]);
    }
    async_load16(&Bm[(size_t)(n0 + r0) * K + k0 + g0 * 8],
                 &Bs[b][(wave * 2 + 0) * 512]);
    async_load16(&Bm[(size_t)(n0 + r1) * K + k0 + g1 * 8],
                 &Bs[b][(wave * 2 + 1) * 512]);
  };

  stage(0, 0);
  stage(1, 1);
  stage(2, 2);

  for (int t = 0; t < KT; ++t) {
    const int rem = KT - 1 - t;
    wait_vm(rem >= 2 ? 12 : (rem == 1 ? 6 : 0));
    __builtin_amdgcn_s_barrier();           // tile t ready for all waves
    __builtin_amdgcn_sched_barrier(0);

    const int buf = t % 3;
    bf16x8 af[4], bfr[4];
#pragma unroll
    for (int i = 0; i < 4; i++) {
      const int ra = tm + i * 16 + lrow;
      const int k7 = ra & 7;
      const float4 fa = *(const float4*)&Asf[buf][ra * 32 + ((s0 ^ k7) << 2)];
      const float4 fb = *(const float4*)&Asf[buf][ra * 32 + (((s0 + 1) ^ k7) << 2)];
      bf16x8 v;
      v[0] = (__bf16)fa.x; v[1] = (__bf16)fa.y; v[2] = (__bf16)fa.z; v[3] = (__bf16)fa.w;
      v[4] = (__bf16)fb.x; v[5] = (__bf16)fb.y; v[6] = (__bf16)fb.z; v[7] = (__bf16)fb.w;
      af[i] = v;
      const int rb = tn + i * 16 + lrow;
      bfr[i] = *(const bf16x8*)&Bs[buf][rb * 32 + ((sB ^ ((rb >> 1) & 3)) << 3)];
    }
#pragma unroll
    for (int i = 0; i < 4; i++)
#pragma unroll
      for (int j = 0; j < 4; j++)
        acc[i][j] = __builtin_amdgcn_mfma_f32_16x16x32_bf16(af[i], bfr[j],
                                                            acc[i][j], 0, 0, 0);
    __builtin_amdgcn_sched_barrier(0);      // reads+MFMA complete above
    __builtin_amdgcn_s_barrier();           // buffer t%3 free
    __builtin_amdgcn_sched_barrier(0);
    if (t + 3 < KT) stage(buf, t + 3);
  }

  const int ccol = lane & 15;
  const int crow = (lane >> 4) * 4;
  float bv[4];
#pragma unroll
  for (int j = 0; j < 4; j++) bv[j] = bias[n0 + tn + j * 16 + ccol];
#pragma unroll
  for (int i = 0; i < 4; i++) {
#pragma unroll
    for (int j = 0; j < 4; j++) {
      const size_t base =
          (size_t)(m0 + tm + i * 16 + crow) * N + (n0 + tn + j * 16 + ccol);
#pragma unroll
      for (int r = 0; r < 4; r++)
        C[base + (size_t)r * N] = (__bf16)(acc[i][j][r] + bv[j]);
    }
  }
}

// Variant B: bf16 A (layer-1 GEMM), same counted-vmcnt ring structure.
__global__ __launch_bounds__(256) void gemm_bt_bias(
    const __bf16* __restrict__ A,   // [M,K]
    const __bf16* __restrict__ Bm,  // [N,K]
    const float* __restrict__ bias, // [N]
    __bf16* __restrict__ C,         // [M,N]
    int M, int N, int K) {
  __shared__ __bf16 As[3][BM * BK];  // 3 x 8 KB
  __shared__ __bf16 Bs[3][BN * BK];  // 3 x 8 KB   (48 KB total)

  const int tid = threadIdx.x;
  const int lane = tid & 63;
  const int wave = tid >> 6;
  const int wg = xcd_swizzle((int)blockIdx.x, (int)gridDim.x);
  const int nb = N / BN;
  const int bm = wg / nb;
  const int bn = wg % nb;
  const int m0 = bm * BM, n0 = bn * BN;

  floatx4 zero = {0.f, 0.f, 0.f, 0.f};
  floatx4 acc[4][4];
#pragma unroll
  for (int i = 0; i < 4; i++)
#pragma unroll
    for (int j = 0; j < 4; j++) acc[i][j] = zero;

  const int e0 = (wave * 2 + 0) * 64 + lane;
  const int e1 = (wave * 2 + 1) * 64 + lane;
  const int r0 = e0 >> 2, g0 = (e0 & 3) ^ ((r0 >> 1) & 3);
  const int r1 = e1 >> 2, g1 = (e1 & 3) ^ ((r1 >> 1) & 3);

  const int tm = (wave >> 1) * 64;
  const int tn = (wave & 1) * 64;
  const int lrow = lane & 15;
  const int lk = (lane >> 4) * 8;
  const int sB = lk >> 3;  // 16B-slot 0..3

  const int KT = K / BK;

  auto stage = [&](int b, int kt) {
    const int k0 = kt * BK;
    async_load16(&A[(size_t)(m0 + r0) * K + k0 + g0 * 8],
                 &As[b][(wave * 2 + 0) * 512]);
    async_load16(&A[(size_t)(m0 + r1) * K + k0 + g1 * 8],
                 &As[b][(wave * 2 + 1) * 512]);
    async_load16(&Bm[(size_t)(n0 + r0) * K + k0 + g0 * 8],
                 &Bs[b][(wave * 2 + 0) * 512]);
    async_load16(&Bm[(size_t)(n0 + r1) * K + k0 + g1 * 8],
                 &Bs[b][(wave * 2 + 1) * 512]);
  };

  stage(0, 0);
  stage(1, 1);
  stage(2, 2);

  for (int t = 0; t < KT; ++t) {
    const int rem = KT - 1 - t;
    wait_vm(rem >= 2 ? 8 : (rem == 1 ? 4 : 0));
    __builtin_amdgcn_s_barrier();
    __builtin_amdgcn_sched_barrier(0);

    const int buf = t % 3;
    bf16x8 af[4], bfr[4];
#pragma unroll
    for (int i = 0; i < 4; i++) {
      const int ra = tm + i * 16 + lrow;
      const int rb = tn + i * 16 + lrow;
      af[i]  = *(const bf16x8*)&As[buf][ra * 32 + ((sB ^ ((ra >> 1) & 3)) << 3)];
      bfr[i] = *(const bf16x8*)&Bs[buf][rb * 32 + ((sB ^ ((rb >> 1) & 3)) << 3)];
    }
#pragma unroll
    for (int i = 0; i < 4; i++)
#pragma unroll
      for (int j = 0; j < 4; j++)
        acc[i][j] = __builtin_amdgcn_mfma_f32_16x16x32_bf16(af[i], bfr[j],
                                                            acc[i][j], 0, 0, 0);
    __builtin_amdgcn_sched_barrier(0);
    __builtin_amdgcn_s_barrier();
    __builtin_amdgcn_sched_barrier(0);
    if (t + 3 < KT) stage(buf, t + 3);
  }

  const int ccol = lane & 15;
  const int crow = (lane >> 4) * 4;
  float bv[4];
#pragma unroll
  for (int j = 0; j < 4; j++) bv[j] = bias[n0 + tn + j * 16 + ccol];
#pragma unroll
  for (int i = 0; i < 4; i++) {
#pragma unroll
    for (int j = 0; j < 4; j++) {
      const size_t base =
          (size_t)(m0 + tm + i * 16 + crow) * N + (n0 + tn + j * 16 + ccol);
#pragma unroll
      for (int r = 0; r < 4; r++)
        C[base + (size_t)r * N] = (__bf16)(acc[i][j][r] + bv[j]);
    }
  }
}

// ---------------------------------------------------------------------------
// IndRNN scan, barrier-free single-wave pipeline (unchanged from round 1:
// 3-deep input LDS pipeline, counted vmcnt, batched wide stores).
// ---------------------------------------------------------------------------
#define TS 64
#define NTILE (T_DIM / TS)  // 16

template <bool BF16OUT>
__global__ __launch_bounds__(64, 1) void scan_kernel(
    const __bf16* __restrict__ pre, // [T, BH] bf16
    const float* __restrict__ h0,   // [BH]
    const float* __restrict__ u,    // [H]
    void* __restrict__ outp,        // [T, BH] bf16 or f32
    float* __restrict__ hn) {       // [BH]
  constexpr int OBYTES = BF16OUT ? 2 : 4;
  __shared__ __bf16 tin[3][TS * 64];          // 24 KB, 3-deep input pipeline
  __shared__ char oraw[2][TS * 64 * OBYTES];  // 16/32 KB output staging

  const int lane = threadIdx.x;
  const int c0 = blockIdx.x * 64;
  const int idx = c0 + lane;
  const float uu = u[idx & (H_DIM - 1)];
  float h = h0[idx];

  const int lrow = lane >> 3;      // 0..7
  const int lcg = (lane & 7) * 8;  // 16B chain sub-offset

  // prologue: tiles 0,1 in flight
#pragma unroll
  for (int i = 0; i < 8; i++)
    async_load16(&pre[(size_t)(i * 8 + lrow) * BH + c0 + lcg], &tin[0][i * 512]);
#pragma unroll
  for (int i = 0; i < 8; i++)
    async_load16(&pre[(size_t)(TS + i * 8 + lrow) * BH + c0 + lcg],
                 &tin[1][i * 512]);

  for (int tile = 0; tile < NTILE; ++tile) {
    __builtin_amdgcn_sched_barrier(0);
    if (tile + 2 < NTILE) {
      const int nb = (tile + 2) % 3;
      const size_t nt0 = (size_t)(tile + 2) * TS;
#pragma unroll
      for (int i = 0; i < 8; i++)
        async_load16(&pre[(nt0 + i * 8 + lrow) * BH + c0 + lcg],
                     &tin[nb][i * 512]);
    }
    // exact younger-op counts (loads=8/tile, flush stores=8 or 16/tile)
    int wv;
    if (BF16OUT)
      wv = (tile == 0 || tile == NTILE - 1) ? 16
         : (tile == 1 || tile == NTILE - 2) ? 24 : 32;
    else
      wv = (tile == 0) ? 16
         : (tile == 1 || tile == NTILE - 1) ? 32
         : (tile == NTILE - 2) ? 40 : 48;
    wait_vm(wv);
    __builtin_amdgcn_sched_barrier(0);

    const int buf = tile % 3;
    const int t0 = tile * TS;
    char* ob = oraw[tile & 1];
#pragma unroll
    for (int s = 0; s < TS; s++) {
      const float p = (float)tin[buf][s * 64 + lane];
      h = fmaxf(fmaf(uu, h, p), 0.0f);
      if (BF16OUT) ((__bf16*)ob)[s * 64 + lane] = (__bf16)h;
      else         ((float*)ob)[s * 64 + lane] = h;
    }
    // flush staged tile: wide coalesced stores
    if (BF16OUT) {
#pragma unroll
      for (int i = 0; i < 8; i++) {
        const int row = i * 8 + (lane >> 3);
        const bf16x8 v =
            *(const bf16x8*)&((const __bf16*)ob)[row * 64 + (lane & 7) * 8];
        *(bf16x8*)&((__bf16*)outp)[(size_t)(t0 + row) * BH + c0 + (lane & 7) * 8] = v;
      }
    } else {
#pragma unroll
      for (int i = 0; i < 16; i++) {
        const int row = i * 4 + (lane >> 4);
        const float4 v =
            *(const float4*)&((const float*)ob)[row * 64 + (lane & 15) * 4];
        *(float4*)&((float*)outp)[(size_t)(t0 + row) * BH + c0 + (lane & 15) * 4] = v;
      }
    }
  }
  hn[idx] = h;
}

// ---------------------------------------------------------------------------
extern "C" void kernel_launch(void* const* d_in, const int* in_sizes, int n_in,
                              void* d_out, int out_size, void* d_ws,
                              size_t ws_size, hipStream_t stream) {
  (void)in_sizes; (void)n_in; (void)out_size; (void)ws_size;
  const float* x      = (const float*)d_in[0]; // [T,B,D]
  const float* hidden = (const float*)d_in[1]; // [L,B,H]
  const float* fc_w   = (const float*)d_in[2]; // [D,D]
  const float* fc_b   = (const float*)d_in[3]; // [D]
  const float* w0     = (const float*)d_in[4]; // [H,D]
  const float* b0     = (const float*)d_in[5]; // [H]
  const float* u0     = (const float*)d_in[6]; // [H]
  const float* w1     = (const float*)d_in[7]; // [H,H]
  const float* b1     = (const float*)d_in[8]; // [H]
  const float* u1     = (const float*)d_in[9]; // [H]
  float* out = (float*)d_out;

  // workspace (~129 MB): pre / out0 (bf16, 64 MB each) + small weights
  char* ws = (char*)d_ws;
  __bf16* pre  = (__bf16*)ws;                   // 64 MB
  __bf16* out0 = (__bf16*)(ws + TBH * 2);       // 64 MB
  char*   tail = ws + 2 * TBH * 2;
  __bf16* Wc    = (__bf16*)tail;                // 512 KB
  __bf16* w1bf  = (__bf16*)(tail + 512 * 1024); // 512 KB
  float*  bcomb = (float*)(tail + 1024 * 1024); // 2 KB

  float* hn = out + TBH; // [2, BH] after out1

  // 1) prep: Wc = w0@fc_w (bf16), w1->bf16, bcomb = b0 + w0@fc_b
  prep_kernel<<<258, 256, 0, stream>>>(w0, fc_w, fc_b, b0, w1, Wc, w1bf, bcomb);
  // 2) pre0 = x @ Wc^T + bcomb -> bf16 (f32->bf16 fused into A staging)
  gemm_a32_bt_bias<<<(TBROWS / BM) * (H_DIM / BN), 256, 0, stream>>>(
      x, Wc, bcomb, pre, TBROWS, H_DIM, D_DIM);
  // 3) layer-0 scan: out0 (bf16), hn[0]
  scan_kernel<true><<<BH / 64, 64, 0, stream>>>(pre, hidden, u0, (void*)out0, hn);
  // 4) pre1 = out0 @ w1^T + b1 -> bf16 (reuse pre buffer)
  gemm_bt_bias<<<(TBROWS / BM) * (H_DIM / BN), 256, 0, stream>>>(
      out0, w1bf, b1, pre, TBROWS, H_DIM, H_DIM);
  // 5) layer-1 scan: out1 (f32) -> d_out, hn[1]
  scan_kernel<false><<<BH / 64, 64, 0, stream>>>(pre, hidden + BH, u1,
                                                 (void*)out, hn + BH);
}

// Round 4
// 448.685 us; speedup vs baseline: 1.0451x; 1.0451x over previous
//
#include <hip/hip_runtime.h>
#include <hip/hip_bf16.h>
#include <cstdint>
#include <cstddef>

// Problem constants (T,B,D,H,L = 1024,64,512,512,2)
#define T_DIM 1024
#define B_DIM 64
#define D_DIM 512
#define H_DIM 512
#define TBROWS (T_DIM * B_DIM)           // 65536 GEMM rows
#define BH (B_DIM * H_DIM)               // 32768
#define TBH ((size_t)T_DIM * (size_t)BH) // 33554432 elements

typedef __bf16 bf16x8 __attribute__((ext_vector_type(8)));
typedef float floatx4 __attribute__((ext_vector_type(4)));

// ---------------------------------------------------------------------------
// async global->LDS, 16B per lane. LDS dest is wave-uniform base + lane*16.
// ---------------------------------------------------------------------------
__device__ __forceinline__ void async_load16(const void* g, void* l) {
  __builtin_amdgcn_global_load_lds(
      (const __attribute__((address_space(1))) unsigned int*)g,
      (__attribute__((address_space(3))) unsigned int*)l,
      16, 0, 0);
}

// counted vmcnt wait (scan kernel only)
__device__ __forceinline__ void wait_vm(int n) {
  switch (n) {
    case 16: asm volatile("s_waitcnt vmcnt(16)" ::: "memory"); break;
    case 24: asm volatile("s_waitcnt vmcnt(24)" ::: "memory"); break;
    case 32: asm volatile("s_waitcnt vmcnt(32)" ::: "memory"); break;
    case 40: asm volatile("s_waitcnt vmcnt(40)" ::: "memory"); break;
    case 48: asm volatile("s_waitcnt vmcnt(48)" ::: "memory"); break;
    default: asm volatile("s_waitcnt vmcnt(0)" ::: "memory"); break;
  }
}

// ---------------------------------------------------------------------------
// Merged prep:
//   blocks [0,128):    Wc[h,d] = sum_e w0[h,e]*fc_w[e,d] (bf16), 8 h-rows/blk
//   blocks [128,256):  w1 -> bf16
//   blocks [256,258):  bcomb[h] = b0[h] + sum_e w0[h,e]*fc_b[e]
// ---------------------------------------------------------------------------
__global__ __launch_bounds__(256) void prep_kernel(
    const float* __restrict__ w0, const float* __restrict__ fc_w,
    const float* __restrict__ fc_b, const float* __restrict__ b0,
    const float* __restrict__ w1, __bf16* __restrict__ Wc,
    __bf16* __restrict__ w1bf, float* __restrict__ bcomb) {
  const int blk = blockIdx.x;
  const int tid = threadIdx.x;
  if (blk < 128) {
    const int h0 = (blk >> 1) * 8;
    const int d = ((blk & 1) << 8) + tid;
    float a[8];
#pragma unroll
    for (int j = 0; j < 8; j++) a[j] = 0.f;
#pragma unroll 4
    for (int e = 0; e < D_DIM; ++e) {
      const float fv = fc_w[(size_t)e * D_DIM + d];
#pragma unroll
      for (int j = 0; j < 8; j++)
        a[j] = fmaf(w0[(size_t)(h0 + j) * D_DIM + e], fv, a[j]);  // w0: s_load
    }
#pragma unroll
    for (int j = 0; j < 8; j++)
      Wc[(size_t)(h0 + j) * D_DIM + d] = (__bf16)a[j];
  } else if (blk < 256) {
    const long i = ((long)(blk - 128) * 256 + tid) * 8;
    const float4 a = *(const float4*)(w1 + i);
    const float4 b = *(const float4*)(w1 + i + 4);
    bf16x8 v;
    v[0] = (__bf16)a.x; v[1] = (__bf16)a.y; v[2] = (__bf16)a.z; v[3] = (__bf16)a.w;
    v[4] = (__bf16)b.x; v[5] = (__bf16)b.y; v[6] = (__bf16)b.z; v[7] = (__bf16)b.w;
    *(bf16x8*)(w1bf + i) = v;
  } else {
    const int h = (blk - 256) * 256 + tid;
    float acc = b0[h];
    const float4* w4 = (const float4*)(w0 + (size_t)h * D_DIM);
#pragma unroll 4
    for (int e = 0; e < D_DIM / 4; ++e) {
      const float4 wv = w4[e];
      acc = fmaf(wv.x, fc_b[e * 4 + 0], acc);
      acc = fmaf(wv.y, fc_b[e * 4 + 1], acc);
      acc = fmaf(wv.z, fc_b[e * 4 + 2], acc);
      acc = fmaf(wv.w, fc_b[e * 4 + 3], acc);
    }
    bcomb[h] = acc;
  }
}

// ---------------------------------------------------------------------------
// GEMMs: 256x256 tile, BK=32, 8 waves (2M x 4N, 128x64 per wave), 16x16x32
// MFMA. Iteration-count reduction is the point: grid 2048->512, per-CU
// latency-exposed iterations 128->32, per-iteration MFMA 16->32 per wave so
// the dbuf prefetch (issued BEFORE compute, drained by the single
// __syncthreads after) actually has compute to hide under.
// Swizzles identical to the verified 128^2 kernels:
//   f32 A tile: 8x16B slots/row, source slot p^(row&7), read slot s^(row&7)
//   bf16 tiles: 4x16B slots/row, source slot p^((row>>1)&3), same on read
// ---------------------------------------------------------------------------
#define BM 256
#define BN 256
#define BK 32

__device__ __forceinline__ int xcd_swizzle(int bid, int nwg) {
  // nwg % 8 == 0 for all launches here -> simple bijective form (m157/m204)
  return (bid & 7) * (nwg >> 3) + (bid >> 3);
}

// Variant A: A is f32 (raw x input), f32->bf16 fused into the fragment path.
__global__ __launch_bounds__(512, 1) void gemm_a32_bt_bias(
    const float* __restrict__ A,    // [M,K] f32
    const __bf16* __restrict__ Bm,  // [N,K] bf16
    const float* __restrict__ bias, // [N]
    __bf16* __restrict__ C,         // [M,N] bf16
    int M, int N, int K) {
  __shared__ float Asf[2][BM * BK];   // 2 x 32 KB
  __shared__ __bf16 Bs[2][BN * BK];   // 2 x 16 KB   (96 KB total)

  const int tid = threadIdx.x;
  const int lane = tid & 63;
  const int wave = tid >> 6;          // 0..7
  const int wg = xcd_swizzle((int)blockIdx.x, (int)gridDim.x);
  const int nb = N / BN;              // 2
  const int bm = wg / nb;
  const int bn = wg % nb;
  const int m0 = bm * BM, n0 = bn * BN;

  floatx4 zero = {0.f, 0.f, 0.f, 0.f};
  floatx4 acc[8][4];
#pragma unroll
  for (int i = 0; i < 8; i++)
#pragma unroll
    for (int j = 0; j < 4; j++) acc[i][j] = zero;

  const int tm = (wave >> 2) * 128;   // 0 / 128
  const int tn = (wave & 3) * 64;     // 0..192
  const int lrow = lane & 15;
  const int lk = (lane >> 4) * 8;
  const int sB = lk >> 3;             // bf16 16B-slot index 0..3
  const int s0 = lk >> 2;             // f32 16B-slot index {0,2,4,6}

  const int KT = K / BK;              // 16

  // ---- stage K-tile at k0 into buffer b (6 loads per wave) ----
  auto stage = [&](int b, int k0) {
    // A: 256 rows x 128B = 2048 16B-units; 4 per wave-lane
#pragma unroll
    for (int i = 0; i < 4; i++) {
      const int e = (wave * 4 + i) * 64 + lane;
      const int r = e >> 3;                    // 0..255
      const int g = (e & 7) ^ (r & 7);         // pre-swizzled source slot
      async_load16(&A[(size_t)(m0 + r) * K + k0 + g * 4],
                   &Asf[b][(wave * 4 + i) * 256]);
    }
    // B: 256 rows x 64B = 1024 16B-units; 2 per wave-lane
#pragma unroll
    for (int i = 0; i < 2; i++) {
      const int e = (wave * 2 + i) * 64 + lane;
      const int r = e >> 2;                    // 0..255
      const int g = (e & 3) ^ ((r >> 1) & 3);
      async_load16(&Bm[(size_t)(n0 + r) * K + k0 + g * 8],
                   &Bs[b][(wave * 2 + i) * 512]);
    }
  };

  stage(0, 0);
  __syncthreads();

  int cur = 0;
  for (int kt = 0; kt < KT; ++kt) {
    if (kt + 1 < KT) stage(cur ^ 1, (kt + 1) * BK);

    bf16x8 af[8], bfr[4];
#pragma unroll
    for (int i = 0; i < 8; i++) {
      const int ra = tm + i * 16 + lrow;
      const int k7 = ra & 7;
      const float4 fa = *(const float4*)&Asf[cur][ra * 32 + ((s0 ^ k7) << 2)];
      const float4 fb = *(const float4*)&Asf[cur][ra * 32 + (((s0 + 1) ^ k7) << 2)];
      bf16x8 v;
      v[0] = (__bf16)fa.x; v[1] = (__bf16)fa.y; v[2] = (__bf16)fa.z; v[3] = (__bf16)fa.w;
      v[4] = (__bf16)fb.x; v[5] = (__bf16)fb.y; v[6] = (__bf16)fb.z; v[7] = (__bf16)fb.w;
      af[i] = v;
    }
#pragma unroll
    for (int j = 0; j < 4; j++) {
      const int rb = tn + j * 16 + lrow;
      bfr[j] = *(const bf16x8*)&Bs[cur][rb * 32 + ((sB ^ ((rb >> 1) & 3)) << 3)];
    }
#pragma unroll
    for (int i = 0; i < 8; i++)
#pragma unroll
      for (int j = 0; j < 4; j++)
        acc[i][j] = __builtin_amdgcn_mfma_f32_16x16x32_bf16(af[i], bfr[j],
                                                            acc[i][j], 0, 0, 0);
    __syncthreads();  // drains this wave's prefetch; compute hid the latency
    cur ^= 1;
  }

  const int ccol = lane & 15;
  const int crow = (lane >> 4) * 4;
  float bv[4];
#pragma unroll
  for (int j = 0; j < 4; j++) bv[j] = bias[n0 + tn + j * 16 + ccol];
#pragma unroll
  for (int i = 0; i < 8; i++) {
#pragma unroll
    for (int j = 0; j < 4; j++) {
      const size_t base =
          (size_t)(m0 + tm + i * 16 + crow) * N + (n0 + tn + j * 16 + ccol);
#pragma unroll
      for (int r = 0; r < 4; r++)
        C[base + (size_t)r * N] = (__bf16)(acc[i][j][r] + bv[j]);
    }
  }
}

// Variant B: bf16 A (layer-1 GEMM), same 256^2 dbuf structure.
__global__ __launch_bounds__(512, 1) void gemm_bt_bias(
    const __bf16* __restrict__ A,   // [M,K]
    const __bf16* __restrict__ Bm,  // [N,K]
    const float* __restrict__ bias, // [N]
    __bf16* __restrict__ C,         // [M,N]
    int M, int N, int K) {
  __shared__ __bf16 As[2][BM * BK];  // 2 x 16 KB
  __shared__ __bf16 Bs[2][BN * BK];  // 2 x 16 KB   (64 KB total)

  const int tid = threadIdx.x;
  const int lane = tid & 63;
  const int wave = tid >> 6;
  const int wg = xcd_swizzle((int)blockIdx.x, (int)gridDim.x);
  const int nb = N / BN;
  const int bm = wg / nb;
  const int bn = wg % nb;
  const int m0 = bm * BM, n0 = bn * BN;

  floatx4 zero = {0.f, 0.f, 0.f, 0.f};
  floatx4 acc[8][4];
#pragma unroll
  for (int i = 0; i < 8; i++)
#pragma unroll
    for (int j = 0; j < 4; j++) acc[i][j] = zero;

  const int tm = (wave >> 2) * 128;
  const int tn = (wave & 3) * 64;
  const int lrow = lane & 15;
  const int lk = (lane >> 4) * 8;
  const int sB = lk >> 3;  // 16B-slot 0..3

  const int KT = K / BK;

  auto stage = [&](int b, int k0) {
    // A and B: 256 rows x 64B each = 1024 16B-units; 2 per wave-lane each
#pragma unroll
    for (int i = 0; i < 2; i++) {
      const int e = (wave * 2 + i) * 64 + lane;
      const int r = e >> 2;
      const int g = (e & 3) ^ ((r >> 1) & 3);
      async_load16(&A[(size_t)(m0 + r) * K + k0 + g * 8],
                   &As[b][(wave * 2 + i) * 512]);
      async_load16(&Bm[(size_t)(n0 + r) * K + k0 + g * 8],
                   &Bs[b][(wave * 2 + i) * 512]);
    }
  };

  stage(0, 0);
  __syncthreads();

  int cur = 0;
  for (int kt = 0; kt < KT; ++kt) {
    if (kt + 1 < KT) stage(cur ^ 1, (kt + 1) * BK);

    bf16x8 af[8], bfr[4];
#pragma unroll
    for (int i = 0; i < 8; i++) {
      const int ra = tm + i * 16 + lrow;
      af[i] = *(const bf16x8*)&As[cur][ra * 32 + ((sB ^ ((ra >> 1) & 3)) << 3)];
    }
#pragma unroll
    for (int j = 0; j < 4; j++) {
      const int rb = tn + j * 16 + lrow;
      bfr[j] = *(const bf16x8*)&Bs[cur][rb * 32 + ((sB ^ ((rb >> 1) & 3)) << 3)];
    }
#pragma unroll
    for (int i = 0; i < 8; i++)
#pragma unroll
      for (int j = 0; j < 4; j++)
        acc[i][j] = __builtin_amdgcn_mfma_f32_16x16x32_bf16(af[i], bfr[j],
                                                            acc[i][j], 0, 0, 0);
    __syncthreads();
    cur ^= 1;
  }

  const int ccol = lane & 15;
  const int crow = (lane >> 4) * 4;
  float bv[4];
#pragma unroll
  for (int j = 0; j < 4; j++) bv[j] = bias[n0 + tn + j * 16 + ccol];
#pragma unroll
  for (int i = 0; i < 8; i++) {
#pragma unroll
    for (int j = 0; j < 4; j++) {
      const size_t base =
          (size_t)(m0 + tm + i * 16 + crow) * N + (n0 + tn + j * 16 + ccol);
#pragma unroll
      for (int r = 0; r < 4; r++)
        C[base + (size_t)r * N] = (__bf16)(acc[i][j][r] + bv[j]);
    }
  }
}

// ---------------------------------------------------------------------------
// IndRNN scan, barrier-free single-wave pipeline (unchanged: 3-deep input
// LDS pipeline, counted vmcnt, batched wide stores).
// ---------------------------------------------------------------------------
#define TS 64
#define NTILE (T_DIM / TS)  // 16

template <bool BF16OUT>
__global__ __launch_bounds__(64, 1) void scan_kernel(
    const __bf16* __restrict__ pre, // [T, BH] bf16
    const float* __restrict__ h0,   // [BH]
    const float* __restrict__ u,    // [H]
    void* __restrict__ outp,        // [T, BH] bf16 or f32
    float* __restrict__ hn) {       // [BH]
  constexpr int OBYTES = BF16OUT ? 2 : 4;
  __shared__ __bf16 tin[3][TS * 64];          // 24 KB, 3-deep input pipeline
  __shared__ char oraw[2][TS * 64 * OBYTES];  // 16/32 KB output staging

  const int lane = threadIdx.x;
  const int c0 = blockIdx.x * 64;
  const int idx = c0 + lane;
  const float uu = u[idx & (H_DIM - 1)];
  float h = h0[idx];

  const int lrow = lane >> 3;      // 0..7
  const int lcg = (lane & 7) * 8;  // 16B chain sub-offset

  // prologue: tiles 0,1 in flight
#pragma unroll
  for (int i = 0; i < 8; i++)
    async_load16(&pre[(size_t)(i * 8 + lrow) * BH + c0 + lcg], &tin[0][i * 512]);
#pragma unroll
  for (int i = 0; i < 8; i++)
    async_load16(&pre[(size_t)(TS + i * 8 + lrow) * BH + c0 + lcg],
                 &tin[1][i * 512]);

  for (int tile = 0; tile < NTILE; ++tile) {
    __builtin_amdgcn_sched_barrier(0);
    if (tile + 2 < NTILE) {
      const int nb = (tile + 2) % 3;
      const size_t nt0 = (size_t)(tile + 2) * TS;
#pragma unroll
      for (int i = 0; i < 8; i++)
        async_load16(&pre[(nt0 + i * 8 + lrow) * BH + c0 + lcg],
                     &tin[nb][i * 512]);
    }
    // exact younger-op counts (loads=8/tile, flush stores=8 or 16/tile)
    int wv;
    if (BF16OUT)
      wv = (tile == 0 || tile == NTILE - 1) ? 16
         : (tile == 1 || tile == NTILE - 2) ? 24 : 32;
    else
      wv = (tile == 0) ? 16
         : (tile == 1 || tile == NTILE - 1) ? 32
         : (tile == NTILE - 2) ? 40 : 48;
    wait_vm(wv);
    __builtin_amdgcn_sched_barrier(0);

    const int buf = tile % 3;
    const int t0 = tile * TS;
    char* ob = oraw[tile & 1];
#pragma unroll
    for (int s = 0; s < TS; s++) {
      const float p = (float)tin[buf][s * 64 + lane];
      h = fmaxf(fmaf(uu, h, p), 0.0f);
      if (BF16OUT) ((__bf16*)ob)[s * 64 + lane] = (__bf16)h;
      else         ((float*)ob)[s * 64 + lane] = h;
    }
    // flush staged tile: wide coalesced stores
    if (BF16OUT) {
#pragma unroll
      for (int i = 0; i < 8; i++) {
        const int row = i * 8 + (lane >> 3);
        const bf16x8 v =
            *(const bf16x8*)&((const __bf16*)ob)[row * 64 + (lane & 7) * 8];
        *(bf16x8*)&((__bf16*)outp)[(size_t)(t0 + row) * BH + c0 + (lane & 7) * 8] = v;
      }
    } else {
#pragma unroll
      for (int i = 0; i < 16; i++) {
        const int row = i * 4 + (lane >> 4);
        const float4 v =
            *(const float4*)&((const float*)ob)[row * 64 + (lane & 15) * 4];
        *(float4*)&((float*)outp)[(size_t)(t0 + row) * BH + c0 + (lane & 15) * 4] = v;
      }
    }
  }
  hn[idx] = h;
}

// ---------------------------------------------------------------------------
extern "C" void kernel_launch(void* const* d_in, const int* in_sizes, int n_in,
                              void* d_out, int out_size, void* d_ws,
                              size_t ws_size, hipStream_t stream) {
  (void)in_sizes; (void)n_in; (void)out_size; (void)ws_size;
  const float* x      = (const float*)d_in[0]; // [T,B,D]
  const float* hidden = (const float*)d_in[1]; // [L,B,H]
  const float* fc_w   = (const float*)d_in[2]; // [D,D]
  const float* fc_b   = (const float*)d_in[3]; // [D]
  const float* w0     = (const float*)d_in[4]; // [H,D]
  const float* b0     = (const float*)d_in[5]; // [H]
  const float* u0     = (const float*)d_in[6]; // [H]
  const float* w1     = (const float*)d_in[7]; // [H,H]
  const float* b1     = (const float*)d_in[8]; // [H]
  const float* u1     = (const float*)d_in[9]; // [H]
  float* out = (float*)d_out;

  // workspace (~129 MB): pre / out0 (bf16, 64 MB each) + small weights
  char* ws = (char*)d_ws;
  __bf16* pre  = (__bf16*)ws;                   // 64 MB
  __bf16* out0 = (__bf16*)(ws + TBH * 2);       // 64 MB
  char*   tail = ws + 2 * TBH * 2;
  __bf16* Wc    = (__bf16*)tail;                // 512 KB
  __bf16* w1bf  = (__bf16*)(tail + 512 * 1024); // 512 KB
  float*  bcomb = (float*)(tail + 1024 * 1024); // 2 KB

  float* hn = out + TBH; // [2, BH] after out1

  // 1) prep: Wc = w0@fc_w (bf16), w1->bf16, bcomb = b0 + w0@fc_b
  prep_kernel<<<258, 256, 0, stream>>>(w0, fc_w, fc_b, b0, w1, Wc, w1bf, bcomb);
  // 2) pre0 = x @ Wc^T + bcomb -> bf16 (f32->bf16 fused into A staging)
  gemm_a32_bt_bias<<<(TBROWS / BM) * (H_DIM / BN), 512, 0, stream>>>(
      x, Wc, bcomb, pre, TBROWS, H_DIM, D_DIM);
  // 3) layer-0 scan: out0 (bf16), hn[0]
  scan_kernel<true><<<BH / 64, 64, 0, stream>>>(pre, hidden, u0, (void*)out0, hn);
  // 4) pre1 = out0 @ w1^T + b1 -> bf16 (reuse pre buffer)
  gemm_bt_bias<<<(TBROWS / BM) * (H_DIM / BN), 512, 0, stream>>>(
      out0, w1bf, b1, pre, TBROWS, H_DIM, H_DIM);
  // 5) layer-1 scan: out1 (f32) -> d_out, hn[1]
  scan_kernel<false><<<BH / 64, 64, 0, stream>>>(pre, hidden + BH, u1,
                                                 (void*)out, hn + BH);
}